// Round 2
// baseline (757.740 us; speedup 1.0000x reference)
//
#include <hip/hip_runtime.h>

#define NN 65536
#define NE 1048576
#define HID 80

// ---------------- input projection: h = x @ W_in + b_in ----------------
__global__ __launch_bounds__(256) void k_in(const float* __restrict__ x,
    const float* __restrict__ W, const float* __restrict__ b,
    float* __restrict__ h) {
  int idx = blockIdx.x * 256 + threadIdx.x;
  if (idx >= NN * HID) return;
  int n = idx / HID, c = idx % HID;
  const float* xr = x + n * 16;
  float acc = b[c];
#pragma unroll
  for (int i = 0; i < 16; i++) acc += xr[i] * W[i * HID + c];
  h[idx] = acc;
}

// ---------------- CSR build ----------------
__global__ __launch_bounds__(256) void k_hist(const int* __restrict__ dst,
                                              int* __restrict__ counts) {
  int idx = blockIdx.x * 256 + threadIdx.x;
  if (idx < NE) atomicAdd(&counts[dst[idx]], 1);
}

// 64 blocks x 256 threads; each thread scans 4 counts; block-local exclusive
// offsets to `offsets`, block total to blocksum[64].
__global__ __launch_bounds__(256) void k_scan1(const int* __restrict__ counts,
    int* __restrict__ offsets, int* __restrict__ blocksum) {
  __shared__ int sc[256];
  int t = threadIdx.x;
  int base = blockIdx.x * 1024 + t * 4;
  int c0 = counts[base], c1 = counts[base + 1], c2 = counts[base + 2],
      c3 = counts[base + 3];
  int s = c0 + c1 + c2 + c3;
  sc[t] = s;
  __syncthreads();
  for (int d = 1; d < 256; d <<= 1) {
    int v = (t >= d) ? sc[t - d] : 0;
    __syncthreads();
    sc[t] += v;
    __syncthreads();
  }
  int excl = sc[t] - s;
  offsets[base] = excl;
  offsets[base + 1] = excl + c0;
  offsets[base + 2] = excl + c0 + c1;
  offsets[base + 3] = excl + c0 + c1 + c2;
  if (t == 255) blocksum[blockIdx.x] = sc[255];
}

// 1 wave scans the 64 block sums -> exclusive bases (in place)
__global__ __launch_bounds__(64) void k_scan2(int* __restrict__ blocksum) {
  int t = threadIdx.x;
  int v = blocksum[t];
  int incl = v;
#pragma unroll
  for (int d = 1; d < 64; d <<= 1) {
    int o = __shfl_up(incl, d, 64);
    if (t >= d) incl += o;
  }
  blocksum[t] = incl - v;
}

// add block bases; init cursors
__global__ __launch_bounds__(256) void k_scan3(int* __restrict__ offsets,
    const int* __restrict__ blocksum, int* __restrict__ cursors) {
  int i = blockIdx.x * 256 + threadIdx.x;
  int v = offsets[i] + blocksum[i >> 10];
  offsets[i] = v;
  cursors[i] = v;
}

__global__ __launch_bounds__(256) void k_fill(const int* __restrict__ src,
    const int* __restrict__ dst, const float4* __restrict__ eattr,
    int* __restrict__ cursors, int* __restrict__ src_sorted,
    float4* __restrict__ eattr_sorted) {
  int idx = blockIdx.x * 256 + threadIdx.x;
  if (idx >= NE) return;
  int d = dst[idx];
  int pos = atomicAdd(&cursors[d], 1);
  src_sorted[pos] = src[idx];
  eattr_sorted[pos] = eattr[idx];
}

// ---------------- per-layer message + aggregate + post-matmul ----------------
// One wave (64 lanes) per node; lane = g*16 + c (g = edge-group, c = channel).
// Phase A: groups split edges 4-way, R_j[c+16i] accumulated in registers.
// Butterfly __shfl_xor(16/32) reduces groups. Group g writes row g to wave-
// private LDS (no barrier: wave-synchronous LDS, in-order per wave).
// Phase B: all 64 lanes compute output comps c2=lane (+64+lane for lane<16).
__global__ __launch_bounds__(256, 8) void k_msg(const float* __restrict__ h_in,
    float* __restrict__ h_out,
    const float* __restrict__ w1, const float* __restrict__ w2,
    const float* __restrict__ w3, const float* __restrict__ w4,
    const int* __restrict__ offsets, const int* __restrict__ counts,
    const int* __restrict__ src_sorted,
    const float4* __restrict__ eattr_sorted) {
  __shared__ float Rlds[4][4][81];  // [wave][j][comp], pad 81
  __shared__ float w1s[1024], w2s[512], w3s[512], w4s[256];
  int tid = threadIdx.x;
  for (int i = tid; i < 1024; i += 256) w1s[i] = w1[i];
  for (int i = tid; i < 512; i += 256) {
    w2s[i] = w2[i];
    w3s[i] = w3[i];
  }
  w4s[tid] = w4[tid];
  __syncthreads();

  const int w = tid >> 6;
  const int lane = tid & 63;
  const int g = lane >> 4;
  const int c = lane & 15;

  // norm constants: 1/sqrt2 * path fan-in norm * 1/sqrt(DEG)
  const float C1 = 0.03125f;      // 1/(sqrt2*sqrt32*4)
  const float C2 = 0.025515518f;  // 1/(sqrt2*sqrt48*4)
  const float C3 = 0.03125f;      // 1/(sqrt2*sqrt32*4)
  const float C4 = 0.044194174f;  // 1/(sqrt2*sqrt16*4)

  int nbase = blockIdx.x * 16 + w * 4;
#pragma unroll 1
  for (int it = 0; it < 4; it++) {
    int n = nbase + it;
    int start = offsets[n];
    int deg = counts[n];
    float R[4][5];
#pragma unroll
    for (int j = 0; j < 4; j++)
#pragma unroll
      for (int i = 0; i < 5; i++) R[j][i] = 0.f;

    for (int e = g; e < deg; e += 4) {
      int rec = start + e;
      int s = src_sorted[rec];
      float4 cf = eattr_sorted[rec];
      const float* hp = h_in + s * HID + c;
      float hv0 = hp[0], hv1 = hp[16], hv2 = hp[32], hv3 = hp[48],
            hv4 = hp[64];
      R[0][0] += cf.x * hv0; R[0][1] += cf.x * hv1; R[0][2] += cf.x * hv2;
      R[0][3] += cf.x * hv3; R[0][4] += cf.x * hv4;
      R[1][0] += cf.y * hv0; R[1][1] += cf.y * hv1; R[1][2] += cf.y * hv2;
      R[1][3] += cf.y * hv3; R[1][4] += cf.y * hv4;
      R[2][0] += cf.z * hv0; R[2][1] += cf.z * hv1; R[2][2] += cf.z * hv2;
      R[2][3] += cf.z * hv3; R[2][4] += cf.z * hv4;
      R[3][0] += cf.w * hv0; R[3][1] += cf.w * hv1; R[3][2] += cf.w * hv2;
      R[3][3] += cf.w * hv3; R[3][4] += cf.w * hv4;
    }

    // reduce the 4 edge-groups
#pragma unroll
    for (int j = 0; j < 4; j++)
#pragma unroll
      for (int i = 0; i < 5; i++) {
        float v = R[j][i];
        v += __shfl_xor(v, 16, 64);
        v += __shfl_xor(v, 32, 64);
        R[j][i] = v;
      }

    // group g writes row g of this wave's LDS slice (parallel, conflict-free)
#pragma unroll
    for (int i = 0; i < 5; i++) Rlds[w][g][c + 16 * i] = R[g][i];

    // ---- post-matmul, wave-synchronous LDS read-back ----
    auto comp = [&](int c2) -> float {
      if (c2 < 32) {
        float a1 = 0.f, a2 = 0.f;
#pragma unroll
        for (int a = 0; a < 32; a++) a1 += Rlds[w][0][a] * w1s[a * 32 + c2];
#pragma unroll
        for (int a = 0; a < 16; a++) {
          float T = Rlds[w][1][32 + 3 * a] + Rlds[w][2][33 + 3 * a] +
                    Rlds[w][3][34 + 3 * a];
          a2 += T * w2s[a * 32 + c2];
        }
        return C1 * a1 + C2 * a2;
      } else {
        int cv = (c2 - 32) / 3, k = (c2 - 32) % 3;
        float a3 = 0.f, a4 = 0.f;
#pragma unroll
        for (int a = 0; a < 32; a++)
          a3 += Rlds[w][k + 1][a] * w3s[a * 16 + cv];
#pragma unroll
        for (int a = 0; a < 16; a++)
          a4 += Rlds[w][0][32 + 3 * a + k] * w4s[a * 16 + cv];
        return C3 * a3 + C4 * a4;
      }
    };
    float* op = h_out + n * HID;
    op[lane] = comp(lane);
    if (lane < 16) op[64 + lane] = comp(64 + lane);
  }
}

// ---------------- output projection: out = relu(h) @ W_out + b_out ----------------
__global__ __launch_bounds__(256) void k_out(const float* __restrict__ h,
    const float* __restrict__ W, const float* __restrict__ b,
    float* __restrict__ out) {
  int idx = blockIdx.x * 256 + threadIdx.x;
  if (idx >= NN * 8) return;
  int n = idx >> 3, c = idx & 7;
  const float* hr = h + n * HID;
  float acc = b[c];
#pragma unroll 8
  for (int a = 0; a < HID; a++) {
    float v = hr[a];
    v = v > 0.f ? v : 0.f;
    acc += v * W[a * 8 + c];
  }
  out[idx] = acc;
}

extern "C" void kernel_launch(void* const* d_in, const int* in_sizes, int n_in,
                              void* d_out, int out_size, void* d_ws,
                              size_t ws_size, hipStream_t stream) {
  const float* x = (const float*)d_in[0];
  const int* ei = (const int*)d_in[1];
  const float* eattr = (const float*)d_in[2];
  const float* W_in = (const float*)d_in[3];
  const float* b_in = (const float*)d_in[4];
  const float* tp_w1 = (const float*)d_in[5];
  const float* tp_w2 = (const float*)d_in[6];
  const float* tp_w3 = (const float*)d_in[7];
  const float* tp_w4 = (const float*)d_in[8];
  const float* W_out = (const float*)d_in[9];
  const float* b_out = (const float*)d_in[10];
  float* out = (float*)d_out;

  char* ws = (char*)d_ws;
  size_t off = 0;
  auto alloc = [&](size_t bytes) {
    void* p = ws + off;
    off += (bytes + 255) & ~size_t(255);
    return p;
  };
  float* h_a = (float*)alloc((size_t)NN * HID * 4);
  float* h_b = (float*)alloc((size_t)NN * HID * 4);
  int* counts = (int*)alloc((size_t)NN * 4);
  int* offsets = (int*)alloc((size_t)NN * 4);
  int* cursors = (int*)alloc((size_t)NN * 4);
  int* blocksum = (int*)alloc(64 * 4);
  int* src_sorted = (int*)alloc((size_t)NE * 4);
  float4* eattr_sorted = (float4*)alloc((size_t)NE * 16);

  const int* src = ei;
  const int* dst = ei + NE;

  hipMemsetAsync(counts, 0, (size_t)NN * 4, stream);
  k_in<<<(NN * HID + 255) / 256, 256, 0, stream>>>(x, W_in, b_in, h_a);
  k_hist<<<NE / 256, 256, 0, stream>>>(dst, counts);
  k_scan1<<<64, 256, 0, stream>>>(counts, offsets, blocksum);
  k_scan2<<<1, 64, 0, stream>>>(blocksum);
  k_scan3<<<256, 256, 0, stream>>>(offsets, blocksum, cursors);
  k_fill<<<NE / 256, 256, 0, stream>>>(src, dst, (const float4*)eattr, cursors,
                                       src_sorted, eattr_sorted);

  float* hin = h_a;
  float* hout = h_b;
  for (int l = 0; l < 3; l++) {
    k_msg<<<NN / 16, 256, 0, stream>>>(hin, hout, tp_w1 + l * 1024,
                                       tp_w2 + l * 512, tp_w3 + l * 512,
                                       tp_w4 + l * 256, offsets, counts,
                                       src_sorted, eattr_sorted);
    float* t = hin;
    hin = hout;
    hout = t;
  }
  k_out<<<(NN * 8 + 255) / 256, 256, 0, stream>>>(hin, W_out, b_out, out);
}

// Round 3
// 659.360 us; speedup vs baseline: 1.1492x; 1.1492x over previous
//
#include <hip/hip_runtime.h>

#define NN 65536
#define NE 1048576
#define HID 80

// ---------------- input projection: h = x @ W_in + b_in ----------------
__global__ __launch_bounds__(256) void k_in(const float* __restrict__ x,
    const float* __restrict__ W, const float* __restrict__ b,
    float* __restrict__ h) {
  int idx = blockIdx.x * 256 + threadIdx.x;
  if (idx >= NN * HID) return;
  int n = idx / HID, c = idx % HID;
  const float* xr = x + n * 16;
  float acc = b[c];
#pragma unroll
  for (int i = 0; i < 16; i++) acc += xr[i] * W[i * HID + c];
  h[idx] = acc;
}

// ---------------- CSR build ----------------
__global__ __launch_bounds__(256) void k_hist(const int* __restrict__ dst,
                                              int* __restrict__ counts) {
  int idx = blockIdx.x * 256 + threadIdx.x;
  if (idx < NE) atomicAdd(&counts[dst[idx]], 1);
}

// 64 blocks x 256 threads; each thread scans 4 counts; block-local exclusive
// offsets to `offsets`, block total to blocksum[64].
__global__ __launch_bounds__(256) void k_scan1(const int* __restrict__ counts,
    int* __restrict__ offsets, int* __restrict__ blocksum) {
  __shared__ int sc[256];
  int t = threadIdx.x;
  int base = blockIdx.x * 1024 + t * 4;
  int c0 = counts[base], c1 = counts[base + 1], c2 = counts[base + 2],
      c3 = counts[base + 3];
  int s = c0 + c1 + c2 + c3;
  sc[t] = s;
  __syncthreads();
  for (int d = 1; d < 256; d <<= 1) {
    int v = (t >= d) ? sc[t - d] : 0;
    __syncthreads();
    sc[t] += v;
    __syncthreads();
  }
  int excl = sc[t] - s;
  offsets[base] = excl;
  offsets[base + 1] = excl + c0;
  offsets[base + 2] = excl + c0 + c1;
  offsets[base + 3] = excl + c0 + c1 + c2;
  if (t == 255) blocksum[blockIdx.x] = sc[255];
}

// 1 wave scans the 64 block sums -> exclusive bases (in place)
__global__ __launch_bounds__(64) void k_scan2(int* __restrict__ blocksum) {
  int t = threadIdx.x;
  int v = blocksum[t];
  int incl = v;
#pragma unroll
  for (int d = 1; d < 64; d <<= 1) {
    int o = __shfl_up(incl, d, 64);
    if (t >= d) incl += o;
  }
  blocksum[t] = incl - v;
}

// add block bases; init cursors
__global__ __launch_bounds__(256) void k_scan3(int* __restrict__ offsets,
    const int* __restrict__ blocksum, int* __restrict__ cursors) {
  int i = blockIdx.x * 256 + threadIdx.x;
  int v = offsets[i] + blocksum[i >> 10];
  offsets[i] = v;
  cursors[i] = v;
}

// scatter only (src, edge_id): 8 B per edge instead of 20 B
__global__ __launch_bounds__(256) void k_fill(const int* __restrict__ src,
    const int* __restrict__ dst, int* __restrict__ cursors,
    int2* __restrict__ edge_rec) {
  int idx = blockIdx.x * 256 + threadIdx.x;
  if (idx >= NE) return;
  int d = dst[idx];
  int pos = atomicAdd(&cursors[d], 1);
  edge_rec[pos] = make_int2(src[idx], idx);
}

// ---------------- per-layer message + aggregate + post-matmul ----------------
// One wave (64 lanes) per node; lane = g*16 + c (g = edge-group, c = channel).
// Phase A: groups split edges 4-way, R_j[c+16i] accumulated in registers.
// Butterfly __shfl_xor(16/32) reduces groups; group g writes row g to wave-
// private LDS (wave-synchronous, no barrier needed).
// Phase B: all 64 lanes compute output comps c2=lane (+64+lane for lane<16).
// launch_bounds(256,4): 128-VGPR budget -- (256,8) caused accumulator spills
// (WRITE_SIZE 482 MB, round 2).
__global__ __launch_bounds__(256, 4) void k_msg(const float* __restrict__ h_in,
    float* __restrict__ h_out, const float4* __restrict__ eattr,
    const float* __restrict__ w1, const float* __restrict__ w2,
    const float* __restrict__ w3, const float* __restrict__ w4,
    const int* __restrict__ offsets, const int* __restrict__ counts,
    const int2* __restrict__ edge_rec) {
  __shared__ float Rlds[4][4][81];  // [wave][j][comp], pad 81
  __shared__ float w1s[1024], w2s[512], w3s[512], w4s[256];
  int tid = threadIdx.x;
  for (int i = tid; i < 1024; i += 256) w1s[i] = w1[i];
  for (int i = tid; i < 512; i += 256) {
    w2s[i] = w2[i];
    w3s[i] = w3[i];
  }
  w4s[tid] = w4[tid];
  __syncthreads();

  const int w = tid >> 6;
  const int lane = tid & 63;
  const int g = lane >> 4;
  const int c = lane & 15;

  // norm constants: 1/sqrt2 * path fan-in norm * 1/sqrt(DEG)
  const float C1 = 0.03125f;      // 1/(sqrt2*sqrt32*4)
  const float C2 = 0.025515518f;  // 1/(sqrt2*sqrt48*4)
  const float C3 = 0.03125f;      // 1/(sqrt2*sqrt32*4)
  const float C4 = 0.044194174f;  // 1/(sqrt2*sqrt16*4)

  int nbase = blockIdx.x * 16 + w * 4;
#pragma unroll 1
  for (int it = 0; it < 4; it++) {
    int n = nbase + it;
    int start = offsets[n];
    int deg = counts[n];
    float R[4][5];
#pragma unroll
    for (int j = 0; j < 4; j++)
#pragma unroll
      for (int i = 0; i < 5; i++) R[j][i] = 0.f;

    for (int e = g; e < deg; e += 4) {
      int2 rec = edge_rec[start + e];
      float4 cf = eattr[rec.y];
      const float* hp = h_in + rec.x * HID + c;
      float hv0 = hp[0], hv1 = hp[16], hv2 = hp[32], hv3 = hp[48],
            hv4 = hp[64];
      R[0][0] += cf.x * hv0; R[0][1] += cf.x * hv1; R[0][2] += cf.x * hv2;
      R[0][3] += cf.x * hv3; R[0][4] += cf.x * hv4;
      R[1][0] += cf.y * hv0; R[1][1] += cf.y * hv1; R[1][2] += cf.y * hv2;
      R[1][3] += cf.y * hv3; R[1][4] += cf.y * hv4;
      R[2][0] += cf.z * hv0; R[2][1] += cf.z * hv1; R[2][2] += cf.z * hv2;
      R[2][3] += cf.z * hv3; R[2][4] += cf.z * hv4;
      R[3][0] += cf.w * hv0; R[3][1] += cf.w * hv1; R[3][2] += cf.w * hv2;
      R[3][3] += cf.w * hv3; R[3][4] += cf.w * hv4;
    }

    // reduce the 4 edge-groups
#pragma unroll
    for (int j = 0; j < 4; j++)
#pragma unroll
      for (int i = 0; i < 5; i++) {
        float v = R[j][i];
        v += __shfl_xor(v, 16, 64);
        v += __shfl_xor(v, 32, 64);
        R[j][i] = v;
      }

    // group g writes row g of this wave's LDS slice (parallel, conflict-free)
#pragma unroll
    for (int i = 0; i < 5; i++) Rlds[w][g][c + 16 * i] = R[g][i];

    // ---- post-matmul, wave-synchronous LDS read-back ----
    auto comp = [&](int c2) -> float {
      if (c2 < 32) {
        float a1 = 0.f, a2 = 0.f;
#pragma unroll
        for (int a = 0; a < 32; a++) a1 += Rlds[w][0][a] * w1s[a * 32 + c2];
#pragma unroll
        for (int a = 0; a < 16; a++) {
          float T = Rlds[w][1][32 + 3 * a] + Rlds[w][2][33 + 3 * a] +
                    Rlds[w][3][34 + 3 * a];
          a2 += T * w2s[a * 32 + c2];
        }
        return C1 * a1 + C2 * a2;
      } else {
        int cv = (c2 - 32) / 3, k = (c2 - 32) % 3;
        float a3 = 0.f, a4 = 0.f;
#pragma unroll
        for (int a = 0; a < 32; a++)
          a3 += Rlds[w][k + 1][a] * w3s[a * 16 + cv];
#pragma unroll
        for (int a = 0; a < 16; a++)
          a4 += Rlds[w][0][32 + 3 * a + k] * w4s[a * 16 + cv];
        return C3 * a3 + C4 * a4;
      }
    };
    float* op = h_out + n * HID;
    op[lane] = comp(lane);
    if (lane < 16) op[64 + lane] = comp(64 + lane);
  }
}

// ---------------- output projection: out = relu(h) @ W_out + b_out ----------------
__global__ __launch_bounds__(256) void k_out(const float* __restrict__ h,
    const float* __restrict__ W, const float* __restrict__ b,
    float* __restrict__ out) {
  int idx = blockIdx.x * 256 + threadIdx.x;
  if (idx >= NN * 8) return;
  int n = idx >> 3, c = idx & 7;
  const float* hr = h + n * HID;
  float acc = b[c];
#pragma unroll 8
  for (int a = 0; a < HID; a++) {
    float v = hr[a];
    v = v > 0.f ? v : 0.f;
    acc += v * W[a * 8 + c];
  }
  out[idx] = acc;
}

extern "C" void kernel_launch(void* const* d_in, const int* in_sizes, int n_in,
                              void* d_out, int out_size, void* d_ws,
                              size_t ws_size, hipStream_t stream) {
  const float* x = (const float*)d_in[0];
  const int* ei = (const int*)d_in[1];
  const float* eattr = (const float*)d_in[2];
  const float* W_in = (const float*)d_in[3];
  const float* b_in = (const float*)d_in[4];
  const float* tp_w1 = (const float*)d_in[5];
  const float* tp_w2 = (const float*)d_in[6];
  const float* tp_w3 = (const float*)d_in[7];
  const float* tp_w4 = (const float*)d_in[8];
  const float* W_out = (const float*)d_in[9];
  const float* b_out = (const float*)d_in[10];
  float* out = (float*)d_out;

  char* ws = (char*)d_ws;
  size_t off = 0;
  auto alloc = [&](size_t bytes) {
    void* p = ws + off;
    off += (bytes + 255) & ~size_t(255);
    return p;
  };
  float* h_a = (float*)alloc((size_t)NN * HID * 4);
  float* h_b = (float*)alloc((size_t)NN * HID * 4);
  int* counts = (int*)alloc((size_t)NN * 4);
  int* offsets = (int*)alloc((size_t)NN * 4);
  int* cursors = (int*)alloc((size_t)NN * 4);
  int* blocksum = (int*)alloc(64 * 4);
  int2* edge_rec = (int2*)alloc((size_t)NE * 8);

  const int* src = ei;
  const int* dst = ei + NE;

  hipMemsetAsync(counts, 0, (size_t)NN * 4, stream);
  k_in<<<(NN * HID + 255) / 256, 256, 0, stream>>>(x, W_in, b_in, h_a);
  k_hist<<<NE / 256, 256, 0, stream>>>(dst, counts);
  k_scan1<<<64, 256, 0, stream>>>(counts, offsets, blocksum);
  k_scan2<<<1, 64, 0, stream>>>(blocksum);
  k_scan3<<<256, 256, 0, stream>>>(offsets, blocksum, cursors);
  k_fill<<<NE / 256, 256, 0, stream>>>(src, dst, cursors, edge_rec);

  float* hin = h_a;
  float* hout = h_b;
  for (int l = 0; l < 3; l++) {
    k_msg<<<NN / 16, 256, 0, stream>>>(hin, hout, (const float4*)eattr,
                                       tp_w1 + l * 1024, tp_w2 + l * 512,
                                       tp_w3 + l * 512, tp_w4 + l * 256,
                                       offsets, counts, edge_rec);
    float* t = hin;
    hin = hout;
    hout = t;
  }
  k_out<<<(NN * 8 + 255) / 256, 256, 0, stream>>>(hin, W_out, b_out, out);
}

// Round 4
// 443.488 us; speedup vs baseline: 1.7086x; 1.4868x over previous
//
#include <hip/hip_runtime.h>

#define NN 65536
#define NE 1048576
#define HID 80

// ---------------- input projection: h = x @ W_in + b_in ----------------
__global__ __launch_bounds__(256) void k_in(const float* __restrict__ x,
    const float* __restrict__ W, const float* __restrict__ b,
    float* __restrict__ h) {
  int idx = blockIdx.x * 256 + threadIdx.x;
  if (idx >= NN * HID) return;
  int n = idx / HID, c = idx % HID;
  const float* xr = x + n * 16;
  float acc = b[c];
#pragma unroll
  for (int i = 0; i < 16; i++) acc += xr[i] * W[i * HID + c];
  h[idx] = acc;
}

// ---------------- CSR build ----------------
__global__ __launch_bounds__(256) void k_hist(const int* __restrict__ dst,
                                              int* __restrict__ counts) {
  int idx = blockIdx.x * 256 + threadIdx.x;
  if (idx < NE) atomicAdd(&counts[dst[idx]], 1);
}

__global__ __launch_bounds__(256) void k_scan1(const int* __restrict__ counts,
    int* __restrict__ offsets, int* __restrict__ blocksum) {
  __shared__ int sc[256];
  int t = threadIdx.x;
  int base = blockIdx.x * 1024 + t * 4;
  int c0 = counts[base], c1 = counts[base + 1], c2 = counts[base + 2],
      c3 = counts[base + 3];
  int s = c0 + c1 + c2 + c3;
  sc[t] = s;
  __syncthreads();
  for (int d = 1; d < 256; d <<= 1) {
    int v = (t >= d) ? sc[t - d] : 0;
    __syncthreads();
    sc[t] += v;
    __syncthreads();
  }
  int excl = sc[t] - s;
  offsets[base] = excl;
  offsets[base + 1] = excl + c0;
  offsets[base + 2] = excl + c0 + c1;
  offsets[base + 3] = excl + c0 + c1 + c2;
  if (t == 255) blocksum[blockIdx.x] = sc[255];
}

__global__ __launch_bounds__(64) void k_scan2(int* __restrict__ blocksum) {
  int t = threadIdx.x;
  int v = blocksum[t];
  int incl = v;
#pragma unroll
  for (int d = 1; d < 64; d <<= 1) {
    int o = __shfl_up(incl, d, 64);
    if (t >= d) incl += o;
  }
  blocksum[t] = incl - v;
}

__global__ __launch_bounds__(256) void k_scan3(int* __restrict__ offsets,
    const int* __restrict__ blocksum, int* __restrict__ cursors) {
  int i = blockIdx.x * 256 + threadIdx.x;
  int v = offsets[i] + blocksum[i >> 10];
  offsets[i] = v;
  cursors[i] = v;
}

// scatter src + eattr together so k_msg streams both sequentially
__global__ __launch_bounds__(256) void k_fill(const int* __restrict__ src,
    const int* __restrict__ dst, const float4* __restrict__ eattr,
    int* __restrict__ cursors, int* __restrict__ src_sorted,
    float4* __restrict__ eattr_sorted) {
  int idx = blockIdx.x * 256 + threadIdx.x;
  if (idx >= NE) return;
  int d = dst[idx];
  int pos = atomicAdd(&cursors[d], 1);
  src_sorted[pos] = src[idx];
  eattr_sorted[pos] = eattr[idx];
}

// ---------------- per-layer message + aggregate + post-matmul ----------------
// Quarter-wave (16 lanes) per node (round-1 structure: streamed edge records,
// no shuffles). Edge loop manually batched x4: 4 independent edges in flight
// per quarter = 16 per wave, to cover the ~400-600 cyc L3-hit gather latency.
// launch_bounds(256,4): 128-VGPR cap, no spills (round-2 lesson).
__global__ __launch_bounds__(256, 4) void k_msg(const float* __restrict__ h_in,
    float* __restrict__ h_out,
    const float* __restrict__ w1, const float* __restrict__ w2,
    const float* __restrict__ w3, const float* __restrict__ w4,
    const int* __restrict__ offsets, const int* __restrict__ counts,
    const int* __restrict__ src_sorted,
    const float4* __restrict__ eattr_sorted) {
  __shared__ float Rlds[16][4][81];  // [node-quarter][j][comp], pad 81
  __shared__ float w1s[1024], w2s[512], w3s[512], w4s[256];
  int tid = threadIdx.x;
  for (int i = tid; i < 1024; i += 256) w1s[i] = w1[i];
  for (int i = tid; i < 512; i += 256) {
    w2s[i] = w2[i];
    w3s[i] = w3[i];
  }
  w4s[tid] = w4[tid];

  int q = tid >> 4;
  int lane = tid & 15;
  int n = (blockIdx.x << 4) + q;

  float R[4][5];
#pragma unroll
  for (int j = 0; j < 4; j++)
#pragma unroll
    for (int i = 0; i < 5; i++) R[j][i] = 0.f;

  int start = offsets[n];
  int deg = counts[n];
  int e = 0;
  for (; e + 4 <= deg; e += 4) {
    int rec = start + e;
    int s0 = src_sorted[rec];
    int s1 = src_sorted[rec + 1];
    int s2 = src_sorted[rec + 2];
    int s3 = src_sorted[rec + 3];
    float4 c0 = eattr_sorted[rec];
    float4 c1 = eattr_sorted[rec + 1];
    float4 c2 = eattr_sorted[rec + 2];
    float4 c3 = eattr_sorted[rec + 3];
    const float* p0 = h_in + s0 * HID + lane;
    const float* p1 = h_in + s1 * HID + lane;
    const float* p2 = h_in + s2 * HID + lane;
    const float* p3 = h_in + s3 * HID + lane;
    float A[5], B[5], C[5], D[5];
#pragma unroll
    for (int i = 0; i < 5; i++) A[i] = p0[16 * i];
#pragma unroll
    for (int i = 0; i < 5; i++) B[i] = p1[16 * i];
#pragma unroll
    for (int i = 0; i < 5; i++) C[i] = p2[16 * i];
#pragma unroll
    for (int i = 0; i < 5; i++) D[i] = p3[16 * i];
#pragma unroll
    for (int i = 0; i < 5; i++) {
      R[0][i] += c0.x * A[i] + c1.x * B[i] + c2.x * C[i] + c3.x * D[i];
      R[1][i] += c0.y * A[i] + c1.y * B[i] + c2.y * C[i] + c3.y * D[i];
      R[2][i] += c0.z * A[i] + c1.z * B[i] + c2.z * C[i] + c3.z * D[i];
      R[3][i] += c0.w * A[i] + c1.w * B[i] + c2.w * C[i] + c3.w * D[i];
    }
  }
  for (; e < deg; e++) {
    int rec = start + e;
    int s = src_sorted[rec];
    float4 cf = eattr_sorted[rec];
    const float* hp = h_in + s * HID + lane;
#pragma unroll
    for (int i = 0; i < 5; i++) {
      float hv = hp[16 * i];
      R[0][i] += cf.x * hv;
      R[1][i] += cf.y * hv;
      R[2][i] += cf.z * hv;
      R[3][i] += cf.w * hv;
    }
  }

#pragma unroll
  for (int j = 0; j < 4; j++)
#pragma unroll
    for (int i = 0; i < 5; i++) Rlds[q][j][lane + 16 * i] = R[j][i];
  __syncthreads();

  // norm constants: 1/sqrt2 * path fan-in norm * 1/sqrt(DEG)
  const float C1 = 0.03125f;       // 1/(sqrt2*sqrt32*4)
  const float C2 = 0.025515518f;   // 1/(sqrt2*sqrt48*4)
  const float C3 = 0.03125f;       // 1/(sqrt2*sqrt32*4)
  const float C4 = 0.044194174f;   // 1/(sqrt2*sqrt16*4)

  float outv[5];
#pragma unroll
  for (int i = 0; i < 5; i++) {
    int c = lane + 16 * i;
    float acc;
    if (c < 32) {  // scalar outputs
      float a1 = 0.f, a2 = 0.f;
#pragma unroll
      for (int a = 0; a < 32; a++) a1 += Rlds[q][0][a] * w1s[a * 32 + c];
#pragma unroll
      for (int a = 0; a < 16; a++) {
        float T = Rlds[q][1][32 + 3 * a] + Rlds[q][2][33 + 3 * a] +
                  Rlds[q][3][34 + 3 * a];
        a2 += T * w2s[a * 32 + c];
      }
      acc = C1 * a1 + C2 * a2;
    } else {  // vector outputs
      int cv = (c - 32) / 3, k = (c - 32) % 3;
      float a3 = 0.f, a4 = 0.f;
#pragma unroll
      for (int a = 0; a < 32; a++) a3 += Rlds[q][k + 1][a] * w3s[a * 16 + cv];
#pragma unroll
      for (int a = 0; a < 16; a++)
        a4 += Rlds[q][0][32 + 3 * a + k] * w4s[a * 16 + cv];
      acc = C3 * a3 + C4 * a4;
    }
    outv[i] = acc;
  }
  float* op = h_out + n * HID + lane;
  op[0] = outv[0];
  op[16] = outv[1];
  op[32] = outv[2];
  op[48] = outv[3];
  op[64] = outv[4];
}

// ---------------- output projection: out = relu(h) @ W_out + b_out ----------------
__global__ __launch_bounds__(256) void k_out(const float* __restrict__ h,
    const float* __restrict__ W, const float* __restrict__ b,
    float* __restrict__ out) {
  int idx = blockIdx.x * 256 + threadIdx.x;
  if (idx >= NN * 8) return;
  int n = idx >> 3, c = idx & 7;
  const float* hr = h + n * HID;
  float acc = b[c];
#pragma unroll 8
  for (int a = 0; a < HID; a++) {
    float v = hr[a];
    v = v > 0.f ? v : 0.f;
    acc += v * W[a * 8 + c];
  }
  out[idx] = acc;
}

extern "C" void kernel_launch(void* const* d_in, const int* in_sizes, int n_in,
                              void* d_out, int out_size, void* d_ws,
                              size_t ws_size, hipStream_t stream) {
  const float* x = (const float*)d_in[0];
  const int* ei = (const int*)d_in[1];
  const float* eattr = (const float*)d_in[2];
  const float* W_in = (const float*)d_in[3];
  const float* b_in = (const float*)d_in[4];
  const float* tp_w1 = (const float*)d_in[5];
  const float* tp_w2 = (const float*)d_in[6];
  const float* tp_w3 = (const float*)d_in[7];
  const float* tp_w4 = (const float*)d_in[8];
  const float* W_out = (const float*)d_in[9];
  const float* b_out = (const float*)d_in[10];
  float* out = (float*)d_out;

  char* ws = (char*)d_ws;
  size_t off = 0;
  auto alloc = [&](size_t bytes) {
    void* p = ws + off;
    off += (bytes + 255) & ~size_t(255);
    return p;
  };
  float* h_a = (float*)alloc((size_t)NN * HID * 4);
  float* h_b = (float*)alloc((size_t)NN * HID * 4);
  int* counts = (int*)alloc((size_t)NN * 4);
  int* offsets = (int*)alloc((size_t)NN * 4);
  int* cursors = (int*)alloc((size_t)NN * 4);
  int* blocksum = (int*)alloc(64 * 4);
  int* src_sorted = (int*)alloc((size_t)NE * 4);
  float4* eattr_sorted = (float4*)alloc((size_t)NE * 16);

  const int* src = ei;
  const int* dst = ei + NE;

  hipMemsetAsync(counts, 0, (size_t)NN * 4, stream);
  k_in<<<(NN * HID + 255) / 256, 256, 0, stream>>>(x, W_in, b_in, h_a);
  k_hist<<<NE / 256, 256, 0, stream>>>(dst, counts);
  k_scan1<<<64, 256, 0, stream>>>(counts, offsets, blocksum);
  k_scan2<<<1, 64, 0, stream>>>(blocksum);
  k_scan3<<<256, 256, 0, stream>>>(offsets, blocksum, cursors);
  k_fill<<<NE / 256, 256, 0, stream>>>(src, dst, (const float4*)eattr, cursors,
                                       src_sorted, eattr_sorted);

  float* hin = h_a;
  float* hout = h_b;
  for (int l = 0; l < 3; l++) {
    k_msg<<<NN / 16, 256, 0, stream>>>(hin, hout, tp_w1 + l * 1024,
                                       tp_w2 + l * 512, tp_w3 + l * 512,
                                       tp_w4 + l * 256, offsets, counts,
                                       src_sorted, eattr_sorted);
    float* t = hin;
    hin = hout;
    hout = t;
  }
  k_out<<<(NN * 8 + 255) / 256, 256, 0, stream>>>(hin, W_out, b_out, out);
}

// Round 5
// 438.946 us; speedup vs baseline: 1.7263x; 1.0103x over previous
//
#include <hip/hip_runtime.h>

#define NN 65536
#define NE 1048576
#define HID 80

typedef unsigned int u32;
typedef unsigned short u16;

__device__ __forceinline__ u16 f2bf(float f) {
  u32 u = __float_as_uint(f);
  u = (u + 0x7fffu + ((u >> 16) & 1u)) >> 16;  // RNE
  return (u16)u;
}
__device__ __forceinline__ float bfhi(u32 packed) {  // high ushort -> float
  return __uint_as_float(packed & 0xffff0000u);
}
__device__ __forceinline__ float bflo(u32 packed) {  // low ushort -> float
  return __uint_as_float(packed << 16);
}

// ---------------- input projection: h = x @ W_in + b_in (bf16 out) ----------------
__global__ __launch_bounds__(256) void k_in(const float* __restrict__ x,
    const float* __restrict__ W, const float* __restrict__ b,
    u16* __restrict__ h) {
  int idx = blockIdx.x * 256 + threadIdx.x;
  if (idx >= NN * HID) return;
  int n = idx / HID, c = idx % HID;
  const float* xr = x + n * 16;
  float acc = b[c];
#pragma unroll
  for (int i = 0; i < 16; i++) acc += xr[i] * W[i * HID + c];
  h[idx] = f2bf(acc);
}

// ---------------- CSR build ----------------
__global__ __launch_bounds__(256) void k_hist(const int* __restrict__ dst,
                                              int* __restrict__ counts) {
  int idx = blockIdx.x * 256 + threadIdx.x;
  if (idx < NE) atomicAdd(&counts[dst[idx]], 1);
}

__global__ __launch_bounds__(256) void k_scan1(const int* __restrict__ counts,
    int* __restrict__ offsets, int* __restrict__ blocksum) {
  __shared__ int sc[256];
  int t = threadIdx.x;
  int base = blockIdx.x * 1024 + t * 4;
  int c0 = counts[base], c1 = counts[base + 1], c2 = counts[base + 2],
      c3 = counts[base + 3];
  int s = c0 + c1 + c2 + c3;
  sc[t] = s;
  __syncthreads();
  for (int d = 1; d < 256; d <<= 1) {
    int v = (t >= d) ? sc[t - d] : 0;
    __syncthreads();
    sc[t] += v;
    __syncthreads();
  }
  int excl = sc[t] - s;
  offsets[base] = excl;
  offsets[base + 1] = excl + c0;
  offsets[base + 2] = excl + c0 + c1;
  offsets[base + 3] = excl + c0 + c1 + c2;
  if (t == 255) blocksum[blockIdx.x] = sc[255];
}

__global__ __launch_bounds__(64) void k_scan2(int* __restrict__ blocksum) {
  int t = threadIdx.x;
  int v = blocksum[t];
  int incl = v;
#pragma unroll
  for (int d = 1; d < 64; d <<= 1) {
    int o = __shfl_up(incl, d, 64);
    if (t >= d) incl += o;
  }
  blocksum[t] = incl - v;
}

__global__ __launch_bounds__(256) void k_scan3(int* __restrict__ offsets,
    const int* __restrict__ blocksum, int* __restrict__ cursors) {
  int i = blockIdx.x * 256 + threadIdx.x;
  int v = offsets[i] + blocksum[i >> 10];
  offsets[i] = v;
  cursors[i] = v;
}

// one 32 B record per edge: [as_float(src), c0, c1, c2] [c3, pad, pad, pad]
// -> single cache-line allocation per scatter (was 2 lines across 2 arrays)
__global__ __launch_bounds__(256) void k_fill(const int* __restrict__ src,
    const int* __restrict__ dst, const float4* __restrict__ eattr,
    int* __restrict__ cursors, float4* __restrict__ erec) {
  int idx = blockIdx.x * 256 + threadIdx.x;
  if (idx >= NE) return;
  int d = dst[idx];
  float4 ea = eattr[idx];
  int pos = atomicAdd(&cursors[d], 1);
  erec[2 * pos] = make_float4(__int_as_float(src[idx]), ea.x, ea.y, ea.z);
  erec[2 * pos + 1] = make_float4(ea.w, 0.f, 0.f, 0.f);
}

// ---------------- per-layer message + aggregate + post-matmul ----------------
// Quarter-wave (16 lanes) per node; 128-thread blocks (8 nodes) -> 19.6 KB LDS,
// 8 blocks/CU. h stored bf16: lane c gathers comps {4c..4c+3, 64+c} via one
// uint2 + one ushort load (2 loads, 2.5 lines/edge vs 5 lines fp32).
// Accumulator->component mapping differs from the post-matmul mapping; the
// component-indexed Rlds transpose makes that free.
// Edge loop batched x4 for MLP. launch_bounds(128,4): 128-VGPR cap, no spills.
__global__ __launch_bounds__(128, 4) void k_msg(const u16* __restrict__ hb_in,
    u16* __restrict__ hb_out,
    const float* __restrict__ w1, const float* __restrict__ w2,
    const float* __restrict__ w3, const float* __restrict__ w4,
    const int* __restrict__ offsets, const int* __restrict__ counts,
    const float* __restrict__ erec) {
  __shared__ float Rlds[8][4][81];
  __shared__ float w1s[1024], w2s[512], w3s[512], w4s[256];
  int tid = threadIdx.x;
  for (int i = tid; i < 1024; i += 128) w1s[i] = w1[i];
  for (int i = tid; i < 512; i += 128) {
    w2s[i] = w2[i];
    w3s[i] = w3[i];
  }
  for (int i = tid; i < 256; i += 128) w4s[i] = w4[i];

  const int q = tid >> 4;
  const int c = tid & 15;
  const int n = blockIdx.x * 8 + q;

  float R[4][5];
#pragma unroll
  for (int j = 0; j < 4; j++)
#pragma unroll
    for (int i = 0; i < 5; i++) R[j][i] = 0.f;

  int start = offsets[n];
  int deg = counts[n];

  int e = 0;
  for (; e + 4 <= deg; e += 4) {
    const float* b0 = erec + (size_t)(start + e) * 8;
    float4 r0 = *(const float4*)(b0);
    float4 r1 = *(const float4*)(b0 + 8);
    float4 r2 = *(const float4*)(b0 + 16);
    float4 r3 = *(const float4*)(b0 + 24);
    float w0 = b0[4], wv1 = b0[12], wv2 = b0[20], wv3 = b0[28];
    const u16* p0 = hb_in + (size_t)__float_as_int(r0.x) * HID;
    const u16* p1 = hb_in + (size_t)__float_as_int(r1.x) * HID;
    const u16* p2 = hb_in + (size_t)__float_as_int(r2.x) * HID;
    const u16* p3 = hb_in + (size_t)__float_as_int(r3.x) * HID;
    uint2 ka = *(const uint2*)(p0 + 4 * c);
    uint2 kb = *(const uint2*)(p1 + 4 * c);
    uint2 kc = *(const uint2*)(p2 + 4 * c);
    uint2 kd = *(const uint2*)(p3 + 4 * c);
    u16 ta = p0[64 + c], tb = p1[64 + c], tc = p2[64 + c], td = p3[64 + c];
    float A[5], B[5], C[5], D[5];
    A[0] = bflo(ka.x); A[1] = bfhi(ka.x); A[2] = bflo(ka.y); A[3] = bfhi(ka.y);
    A[4] = bflo((u32)ta);
    B[0] = bflo(kb.x); B[1] = bfhi(kb.x); B[2] = bflo(kb.y); B[3] = bfhi(kb.y);
    B[4] = bflo((u32)tb);
    C[0] = bflo(kc.x); C[1] = bfhi(kc.x); C[2] = bflo(kc.y); C[3] = bfhi(kc.y);
    C[4] = bflo((u32)tc);
    D[0] = bflo(kd.x); D[1] = bfhi(kd.x); D[2] = bflo(kd.y); D[3] = bfhi(kd.y);
    D[4] = bflo((u32)td);
#pragma unroll
    for (int i = 0; i < 5; i++) {
      R[0][i] += r0.y * A[i] + r1.y * B[i] + r2.y * C[i] + r3.y * D[i];
      R[1][i] += r0.z * A[i] + r1.z * B[i] + r2.z * C[i] + r3.z * D[i];
      R[2][i] += r0.w * A[i] + r1.w * B[i] + r2.w * C[i] + r3.w * D[i];
      R[3][i] += w0 * A[i] + wv1 * B[i] + wv2 * C[i] + wv3 * D[i];
    }
  }
  for (; e < deg; e++) {
    const float* b0 = erec + (size_t)(start + e) * 8;
    float4 r0 = *(const float4*)(b0);
    float w0 = b0[4];
    const u16* p0 = hb_in + (size_t)__float_as_int(r0.x) * HID;
    uint2 ka = *(const uint2*)(p0 + 4 * c);
    u16 ta = p0[64 + c];
    float A[5];
    A[0] = bflo(ka.x); A[1] = bfhi(ka.x); A[2] = bflo(ka.y); A[3] = bfhi(ka.y);
    A[4] = bflo((u32)ta);
#pragma unroll
    for (int i = 0; i < 5; i++) {
      R[0][i] += r0.y * A[i];
      R[1][i] += r0.z * A[i];
      R[2][i] += r0.w * A[i];
      R[3][i] += w0 * A[i];
    }
  }

  // transpose accumulators into component-indexed LDS
#pragma unroll
  for (int j = 0; j < 4; j++) {
#pragma unroll
    for (int i = 0; i < 4; i++) Rlds[q][j][4 * c + i] = R[j][i];
    Rlds[q][j][64 + c] = R[j][4];
  }
  __syncthreads();

  // norm constants: 1/sqrt2 * path fan-in norm * 1/sqrt(DEG)
  const float C1 = 0.03125f;      // 1/(sqrt2*sqrt32*4)
  const float C2 = 0.025515518f;  // 1/(sqrt2*sqrt48*4)
  const float C3 = 0.03125f;      // 1/(sqrt2*sqrt32*4)
  const float C4 = 0.044194174f;  // 1/(sqrt2*sqrt16*4)

#pragma unroll
  for (int i = 0; i < 5; i++) {
    int c2 = c + 16 * i;  // branch-uniform per i across the quarter
    float acc;
    if (c2 < 32) {  // scalar outputs
      float a1 = 0.f, a2 = 0.f;
#pragma unroll
      for (int a = 0; a < 32; a++) a1 += Rlds[q][0][a] * w1s[a * 32 + c2];
#pragma unroll
      for (int a = 0; a < 16; a++) {
        float T = Rlds[q][1][32 + 3 * a] + Rlds[q][2][33 + 3 * a] +
                  Rlds[q][3][34 + 3 * a];
        a2 += T * w2s[a * 32 + c2];
      }
      acc = C1 * a1 + C2 * a2;
    } else {  // vector outputs
      int cv = (c2 - 32) / 3, k = (c2 - 32) % 3;
      float a3 = 0.f, a4 = 0.f;
#pragma unroll
      for (int a = 0; a < 32; a++) a3 += Rlds[q][k + 1][a] * w3s[a * 16 + cv];
#pragma unroll
      for (int a = 0; a < 16; a++)
        a4 += Rlds[q][0][32 + 3 * a + k] * w4s[a * 16 + cv];
      acc = C3 * a3 + C4 * a4;
    }
    hb_out[(size_t)n * HID + c2] = f2bf(acc);
  }
}

// ---------------- output projection: out = relu(h) @ W_out + b_out ----------------
__global__ __launch_bounds__(256) void k_out(const u16* __restrict__ h,
    const float* __restrict__ W, const float* __restrict__ b,
    float* __restrict__ out) {
  int idx = blockIdx.x * 256 + threadIdx.x;
  if (idx >= NN * 8) return;
  int n = idx >> 3, c = idx & 7;
  const u16* hr = h + (size_t)n * HID;
  float acc = b[c];
#pragma unroll 8
  for (int a = 0; a < HID; a++) {
    float v = bflo((u32)hr[a]);
    v = v > 0.f ? v : 0.f;
    acc += v * W[a * 8 + c];
  }
  out[idx] = acc;
}

extern "C" void kernel_launch(void* const* d_in, const int* in_sizes, int n_in,
                              void* d_out, int out_size, void* d_ws,
                              size_t ws_size, hipStream_t stream) {
  const float* x = (const float*)d_in[0];
  const int* ei = (const int*)d_in[1];
  const float* eattr = (const float*)d_in[2];
  const float* W_in = (const float*)d_in[3];
  const float* b_in = (const float*)d_in[4];
  const float* tp_w1 = (const float*)d_in[5];
  const float* tp_w2 = (const float*)d_in[6];
  const float* tp_w3 = (const float*)d_in[7];
  const float* tp_w4 = (const float*)d_in[8];
  const float* W_out = (const float*)d_in[9];
  const float* b_out = (const float*)d_in[10];
  float* out = (float*)d_out;

  char* ws = (char*)d_ws;
  size_t off = 0;
  auto alloc = [&](size_t bytes) {
    void* p = ws + off;
    off += (bytes + 255) & ~size_t(255);
    return p;
  };
  u16* h_a = (u16*)alloc((size_t)NN * HID * 2);
  u16* h_b = (u16*)alloc((size_t)NN * HID * 2);
  int* counts = (int*)alloc((size_t)NN * 4);
  int* offsets = (int*)alloc((size_t)NN * 4);
  int* cursors = (int*)alloc((size_t)NN * 4);
  int* blocksum = (int*)alloc(64 * 4);
  float4* erec = (float4*)alloc((size_t)NE * 32);

  const int* src = ei;
  const int* dst = ei + NE;

  hipMemsetAsync(counts, 0, (size_t)NN * 4, stream);
  k_in<<<(NN * HID + 255) / 256, 256, 0, stream>>>(x, W_in, b_in, h_a);
  k_hist<<<NE / 256, 256, 0, stream>>>(dst, counts);
  k_scan1<<<64, 256, 0, stream>>>(counts, offsets, blocksum);
  k_scan2<<<1, 64, 0, stream>>>(blocksum);
  k_scan3<<<256, 256, 0, stream>>>(offsets, blocksum, cursors);
  k_fill<<<NE / 256, 256, 0, stream>>>(src, dst, (const float4*)eattr, cursors,
                                       erec);

  u16* hin = h_a;
  u16* hout = h_b;
  for (int l = 0; l < 3; l++) {
    k_msg<<<NN / 8, 128, 0, stream>>>(hin, hout, tp_w1 + l * 1024,
                                      tp_w2 + l * 512, tp_w3 + l * 512,
                                      tp_w4 + l * 256, offsets, counts,
                                      (const float*)erec);
    u16* t = hin;
    hin = hout;
    hout = t;
  }
  k_out<<<(NN * 8 + 255) / 256, 256, 0, stream>>>(hin, W_out, b_out, out);
}